// Round 2
// baseline (440.192 us; speedup 1.0000x reference)
//
#include <hip/hip_runtime.h>
#include <stdint.h>

typedef __attribute__((ext_vector_type(8))) short short8;
typedef __attribute__((ext_vector_type(4))) float floatx4;

#define DEV static __device__ __forceinline__

constexpr int Bb = 32, Pp = 577, Dd = 768, Hh = 12;
constexpr int M_VALID = Bb * Pp;      // 18464
constexpr int M_PAD   = 18560;        // 145 * 128
constexpr float SCALE = 0.10206207261596577f;  // (768/8)^-0.5 = 96^-0.5

DEV ushort f2b(float f) {
  union { float f; uint32_t u; } c; c.f = f;
  uint32_t u = c.u + 0x7fffu + ((c.u >> 16) & 1u);
  return (ushort)(u >> 16);
}

// ---------------- fp32 -> bf16 conversion with zero padding ----------------
__global__ void cvt_pad(const float* __restrict__ src, ushort* __restrict__ dst,
                        int n_valid4, int n_total4) {
  const float4* s4 = (const float4*)src;
  for (int i = blockIdx.x * blockDim.x + threadIdx.x; i < n_total4;
       i += gridDim.x * blockDim.x) {
    float4 v = make_float4(0.f, 0.f, 0.f, 0.f);
    if (i < n_valid4) v = s4[i];
    ushort4 o;
    o.x = f2b(v.x); o.y = f2b(v.y); o.z = f2b(v.z); o.w = f2b(v.w);
    ((ushort4*)dst)[i] = o;
  }
}

// ---------------- bf16 GEMM: C[M,N] = A[M,K] * B[N,K]^T + bias -------------
// m97 structure: 128x128 tile, BK=32, 4 waves (2x2), global_load_lds width 16.
template<bool C_F32>
__global__ __launch_bounds__(256) void gemm_bt(
    const ushort* __restrict__ A, const ushort* __restrict__ Bw,
    const float* __restrict__ bias, void* __restrict__ Cout,
    int N, int K, int m_valid)
{
  __shared__ ushort As[128 * 32];
  __shared__ ushort Bs[128 * 32];
  const int tid = threadIdx.x;
  const int lane = tid & 63;
  const int w = tid >> 6;
  const int wr = w >> 1, wc = w & 1;
  const int llo = lane & 15, lhi = lane >> 4;
  const int m0 = blockIdx.x * 128, n0 = blockIdx.y * 128;

  floatx4 acc[4][4];
#pragma unroll
  for (int i = 0; i < 4; ++i)
#pragma unroll
    for (int j = 0; j < 4; ++j) acc[i][j] = floatx4{0.f, 0.f, 0.f, 0.f};

  const int srow = tid >> 2;          // 0..63
  const int scol = (tid & 3) * 8;     // element offset within 32-wide K slab
  const ushort* gA0 = A  + (size_t)(m0 + srow) * K + scol;
  const ushort* gA1 = A  + (size_t)(m0 + 64 + srow) * K + scol;
  const ushort* gB0 = Bw + (size_t)(n0 + srow) * K + scol;
  const ushort* gB1 = Bw + (size_t)(n0 + 64 + srow) * K + scol;
  ushort* lA0 = As + tid * 8;
  ushort* lA1 = As + 2048 + tid * 8;
  ushort* lB0 = Bs + tid * 8;
  ushort* lB1 = Bs + 2048 + tid * 8;

  for (int kk = 0; kk < K; kk += 32) {
    __builtin_amdgcn_global_load_lds(
        (const __attribute__((address_space(1))) void*)(gA0 + kk),
        (__attribute__((address_space(3))) void*)lA0, 16, 0, 0);
    __builtin_amdgcn_global_load_lds(
        (const __attribute__((address_space(1))) void*)(gA1 + kk),
        (__attribute__((address_space(3))) void*)lA1, 16, 0, 0);
    __builtin_amdgcn_global_load_lds(
        (const __attribute__((address_space(1))) void*)(gB0 + kk),
        (__attribute__((address_space(3))) void*)lB0, 16, 0, 0);
    __builtin_amdgcn_global_load_lds(
        (const __attribute__((address_space(1))) void*)(gB1 + kk),
        (__attribute__((address_space(3))) void*)lB1, 16, 0, 0);
    __syncthreads();

    short8 af[4], bfr[4];
#pragma unroll
    for (int i = 0; i < 4; ++i) {
      af[i]  = *(const short8*)(As + (wr * 64 + i * 16 + llo) * 32 + lhi * 8);
      bfr[i] = *(const short8*)(Bs + (wc * 64 + i * 16 + llo) * 32 + lhi * 8);
    }
#pragma unroll
    for (int i = 0; i < 4; ++i)
#pragma unroll
      for (int j = 0; j < 4; ++j)
        acc[i][j] = __builtin_amdgcn_mfma_f32_16x16x32_bf16(af[i], bfr[j], acc[i][j], 0, 0, 0);
    __syncthreads();
  }

  float bv[4];
#pragma unroll
  for (int j = 0; j < 4; ++j) bv[j] = bias[n0 + wc * 64 + j * 16 + llo];

#pragma unroll
  for (int i = 0; i < 4; ++i) {
#pragma unroll
    for (int r = 0; r < 4; ++r) {
      const int row = m0 + wr * 64 + i * 16 + lhi * 4 + r;
      if (C_F32 && row >= m_valid) continue;
      const size_t rb = (size_t)row * N + n0 + wc * 64;
#pragma unroll
      for (int j = 0; j < 4; ++j) {
        float v = acc[i][j][r] + bv[j];
        if (C_F32) ((float*)Cout)[rb + j * 16 + llo] = v;
        else       ((ushort*)Cout)[rb + j * 16 + llo] = f2b(v);
      }
    }
  }
}

// ---------------- flash attention ------------------------------------------
// qkv layout per row of C1 (2304 wide): [v(0..767) | q(768..1535) | k(1536..2303)]
// each 768 block is h*64 + ss. Block: 64 q-rows of one (b,h); 4 waves x 16 rows.
__global__ __launch_bounds__(256) void attn_fwd(
    const ushort* __restrict__ C1, ushort* __restrict__ O)
{
  const int qt = blockIdx.x, h = blockIdx.y, b = blockIdx.z;
  const int tid = threadIdx.x;
  const int lane = tid & 63, w = tid >> 6;
  const int llo = lane & 15, lhi = lane >> 4;

  __shared__ ushort Ks[64][72];      // K rows (kv-local), padded -> 2-way max
  __shared__ ushort Vt[64][72];      // V transposed: Vt[ss][p_local]
  __shared__ ushort Ps[4][16][72];   // per-wave P tile

  const int q0 = qt * 64;
  const int qrow = q0 + w * 16 + llo;            // may exceed 576: finite garbage, never stored
  const size_t qoff = (size_t)(b * Pp + qrow) * 2304 + 768 + h * 64;
  const short8 qf0 = *(const short8*)(C1 + qoff + lhi * 8);
  const short8 qf1 = *(const short8*)(C1 + qoff + 32 + lhi * 8);

  float m_r[4], l_r[4];
  floatx4 acc_o[4];
#pragma unroll
  for (int r = 0; r < 4; ++r) { m_r[r] = -3.0e38f; l_r[r] = 0.f; }
#pragma unroll
  for (int st = 0; st < 4; ++st) acc_o[st] = floatx4{0.f, 0.f, 0.f, 0.f};

  const int srow = tid >> 2;          // 0..63
  const int sc16 = (tid & 3) * 16;    // 16 elements/thread -> full 64-wide rows

  for (int t = 0; t < 10; ++t) {
    const int kvrow = t * 64 + srow;  // may exceed 576; masked by column check
    const size_t kvoff = (size_t)(b * Pp + kvrow) * 2304 + h * 64 + sc16;
    const short8 k0 = *(const short8*)(C1 + kvoff + 1536);
    const short8 k1 = *(const short8*)(C1 + kvoff + 1536 + 8);
    const short8 v0 = *(const short8*)(C1 + kvoff);
    const short8 v1 = *(const short8*)(C1 + kvoff + 8);
    __syncthreads();                  // prev iter PV reads done
    *(short8*)&Ks[srow][sc16] = k0;
    *(short8*)&Ks[srow][sc16 + 8] = k1;
#pragma unroll
    for (int i = 0; i < 8; ++i) {
      Vt[sc16 + i][srow] = (ushort)v0[i];
      Vt[sc16 + 8 + i][srow] = (ushort)v1[i];
    }
    __syncthreads();

    // S = Q K^T  (16 rows x 64 cols per wave)
    float sv[4][4];                   // [ntile][r]
#pragma unroll
    for (int ntl = 0; ntl < 4; ++ntl) {
      floatx4 acc = floatx4{0.f, 0.f, 0.f, 0.f};
      const short8 bf0 = *(const short8*)&Ks[ntl * 16 + llo][lhi * 8];
      const short8 bf1 = *(const short8*)&Ks[ntl * 16 + llo][32 + lhi * 8];
      acc = __builtin_amdgcn_mfma_f32_16x16x32_bf16(qf0, bf0, acc, 0, 0, 0);
      acc = __builtin_amdgcn_mfma_f32_16x16x32_bf16(qf1, bf1, acc, 0, 0, 0);
      const bool valid = (t * 64 + ntl * 16 + llo) < Pp;
#pragma unroll
      for (int r = 0; r < 4; ++r)
        sv[ntl][r] = valid ? acc[r] * SCALE : -3.0e38f;
    }

    // online softmax; row (lhi*4+r) lives across the 16 lanes sharing lhi
#pragma unroll
    for (int r = 0; r < 4; ++r) {
      float mx = fmaxf(fmaxf(sv[0][r], sv[1][r]), fmaxf(sv[2][r], sv[3][r]));
#pragma unroll
      for (int off = 1; off < 16; off <<= 1) mx = fmaxf(mx, __shfl_xor(mx, off, 64));
      const float mnew = fmaxf(m_r[r], mx);
      const float corr = __expf(m_r[r] - mnew);
      float ps = 0.f;
#pragma unroll
      for (int ntl = 0; ntl < 4; ++ntl) {
        const float p = __expf(sv[ntl][r] - mnew);
        sv[ntl][r] = p;
        ps += p;
      }
#pragma unroll
      for (int off = 1; off < 16; off <<= 1) ps += __shfl_xor(ps, off, 64);
      l_r[r] = l_r[r] * corr + ps;
      m_r[r] = mnew;
#pragma unroll
      for (int st = 0; st < 4; ++st) acc_o[st][r] *= corr;
    }

    // P -> LDS (bf16) for A-fragment repack
#pragma unroll
    for (int r = 0; r < 4; ++r)
#pragma unroll
      for (int ntl = 0; ntl < 4; ++ntl)
        Ps[w][lhi * 4 + r][ntl * 16 + llo] = f2b(sv[ntl][r]);
    __syncthreads();

    // O += P V
    const short8 pa0 = *(const short8*)&Ps[w][llo][lhi * 8];
    const short8 pa1 = *(const short8*)&Ps[w][llo][32 + lhi * 8];
#pragma unroll
    for (int st = 0; st < 4; ++st) {
      const short8 vb0 = *(const short8*)&Vt[st * 16 + llo][lhi * 8];
      const short8 vb1 = *(const short8*)&Vt[st * 16 + llo][32 + lhi * 8];
      acc_o[st] = __builtin_amdgcn_mfma_f32_16x16x32_bf16(pa0, vb0, acc_o[st], 0, 0, 0);
      acc_o[st] = __builtin_amdgcn_mfma_f32_16x16x32_bf16(pa1, vb1, acc_o[st], 0, 0, 0);
    }
  }

#pragma unroll
  for (int r = 0; r < 4; ++r) {
    const int p = q0 + w * 16 + lhi * 4 + r;
    if (p < Pp) {
      const float inv = 1.f / l_r[r];
      const size_t ob = (size_t)(b * Pp + p) * Dd + h * 64;
#pragma unroll
      for (int st = 0; st < 4; ++st)
        O[ob + st * 16 + llo] = f2b(acc_o[st][r] * inv);
    }
  }
}

// ---------------- launch ----------------------------------------------------
extern "C" void kernel_launch(void* const* d_in, const int* in_sizes, int n_in,
                              void* d_out, int out_size, void* d_ws, size_t ws_size,
                              hipStream_t stream) {
  const float* x     = (const float*)d_in[0];
  const float* qkv_w = (const float*)d_in[1];
  const float* qkv_b = (const float*)d_in[2];
  const float* out_w = (const float*)d_in[3];
  const float* out_b = (const float*)d_in[4];
  float* out = (float*)d_out;

  char* ws = (char*)d_ws;
  size_t off = 0;
  ushort* C1b = (ushort*)(ws + off); off += (size_t)M_PAD * 2304 * 2;   // 85.5 MB
  ushort* W1b = (ushort*)(ws + off); off += (size_t)2304 * 768 * 2;     // 3.5 MB
  ushort* W3b = (ushort*)(ws + off); off += (size_t)768 * 768 * 2;      // 1.2 MB
  ushort* Xb  = (ushort*)(ws + off); off += (size_t)M_PAD * 768 * 2;    // 28.5 MB
  ushort* Ob  = Xb;  // reuse: Xb dead after QKV GEMM, attention output takes it

  cvt_pad<<<2048, 256, 0, stream>>>(x, Xb, M_VALID * 768 / 4, M_PAD * 768 / 4);
  cvt_pad<<<1024, 256, 0, stream>>>(qkv_w, W1b, 2304 * 768 / 4, 2304 * 768 / 4);
  cvt_pad<<<512, 256, 0, stream>>>(out_w, W3b, 768 * 768 / 4, 768 * 768 / 4);

  gemm_bt<false><<<dim3(145, 18), 256, 0, stream>>>(Xb, W1b, qkv_b, (void*)C1b,
                                                    2304, 768, M_PAD);
  attn_fwd<<<dim3(10, 12, 32), 256, 0, stream>>>(C1b, Ob);
  gemm_bt<true><<<dim3(145, 6), 256, 0, stream>>>(Ob, W3b, out_b, (void*)out,
                                                  768, 768, M_VALID);
}

// Round 3
// 384.479 us; speedup vs baseline: 1.1449x; 1.1449x over previous
//
#include <hip/hip_runtime.h>
#include <stdint.h>

typedef __attribute__((ext_vector_type(8))) short short8;
typedef __attribute__((ext_vector_type(4))) float floatx4;

#define DEV static __device__ __forceinline__

constexpr int Bb = 32, Pp = 577, Dd = 768, Hh = 12;
constexpr int M_VALID = Bb * Pp;      // 18464
constexpr int M_PAD   = 18560;        // 145 * 128
constexpr int PKV     = 640;          // padded kv length (10 * 64)
constexpr float SCALE = 0.10206207261596577f;  // 96^-0.5

DEV ushort f2b(float f) {
  union { float f; uint32_t u; } c; c.f = f;
  uint32_t u = c.u + 0x7fffu + ((c.u >> 16) & 1u);
  return (ushort)(u >> 16);
}

// ---------------- fp32 -> bf16 conversion with zero padding ----------------
__global__ void cvt_pad(const float* __restrict__ src, ushort* __restrict__ dst,
                        int n_valid4, int n_total4) {
  const float4* s4 = (const float4*)src;
  for (int i = blockIdx.x * blockDim.x + threadIdx.x; i < n_total4;
       i += gridDim.x * blockDim.x) {
    float4 v = make_float4(0.f, 0.f, 0.f, 0.f);
    if (i < n_valid4) v = s4[i];
    ushort4 o;
    o.x = f2b(v.x); o.y = f2b(v.y); o.z = f2b(v.z); o.w = f2b(v.w);
    ((ushort4*)dst)[i] = o;
  }
}

// ---------------- bf16 GEMM: C[M,N] = A[M,K] * B[N,K]^T + bias -------------
// m97 structure: 128x128 tile, BK=32, 4 waves (2x2), global_load_lds width 16.
// A has row stride lda (>= K).
template<bool C_F32>
__global__ __launch_bounds__(256) void gemm_bt(
    const ushort* __restrict__ A, int lda,
    const ushort* __restrict__ Bw,
    const float* __restrict__ bias, void* __restrict__ Cout,
    int N, int K, int m_valid)
{
  __shared__ ushort As[128 * 32];
  __shared__ ushort Bs[128 * 32];
  const int tid = threadIdx.x;
  const int lane = tid & 63;
  const int w = tid >> 6;
  const int wr = w >> 1, wc = w & 1;
  const int llo = lane & 15, lhi = lane >> 4;
  const int m0 = blockIdx.x * 128, n0 = blockIdx.y * 128;

  floatx4 acc[4][4];
#pragma unroll
  for (int i = 0; i < 4; ++i)
#pragma unroll
    for (int j = 0; j < 4; ++j) acc[i][j] = floatx4{0.f, 0.f, 0.f, 0.f};

  const int srow = tid >> 2;          // 0..63
  const int scol = (tid & 3) * 8;     // element offset within 32-wide K slab
  const ushort* gA0 = A  + (size_t)(m0 + srow) * lda + scol;
  const ushort* gA1 = A  + (size_t)(m0 + 64 + srow) * lda + scol;
  const ushort* gB0 = Bw + (size_t)(n0 + srow) * K + scol;
  const ushort* gB1 = Bw + (size_t)(n0 + 64 + srow) * K + scol;
  ushort* lA0 = As + tid * 8;
  ushort* lA1 = As + 2048 + tid * 8;
  ushort* lB0 = Bs + tid * 8;
  ushort* lB1 = Bs + 2048 + tid * 8;

  for (int kk = 0; kk < K; kk += 32) {
    __builtin_amdgcn_global_load_lds(
        (const __attribute__((address_space(1))) void*)(gA0 + kk),
        (__attribute__((address_space(3))) void*)lA0, 16, 0, 0);
    __builtin_amdgcn_global_load_lds(
        (const __attribute__((address_space(1))) void*)(gA1 + kk),
        (__attribute__((address_space(3))) void*)lA1, 16, 0, 0);
    __builtin_amdgcn_global_load_lds(
        (const __attribute__((address_space(1))) void*)(gB0 + kk),
        (__attribute__((address_space(3))) void*)lB0, 16, 0, 0);
    __builtin_amdgcn_global_load_lds(
        (const __attribute__((address_space(1))) void*)(gB1 + kk),
        (__attribute__((address_space(3))) void*)lB1, 16, 0, 0);
    __syncthreads();

    short8 af[4], bfr[4];
#pragma unroll
    for (int i = 0; i < 4; ++i) {
      af[i]  = *(const short8*)(As + (wr * 64 + i * 16 + llo) * 32 + lhi * 8);
      bfr[i] = *(const short8*)(Bs + (wc * 64 + i * 16 + llo) * 32 + lhi * 8);
    }
#pragma unroll
    for (int i = 0; i < 4; ++i)
#pragma unroll
      for (int j = 0; j < 4; ++j)
        acc[i][j] = __builtin_amdgcn_mfma_f32_16x16x32_bf16(af[i], bfr[j], acc[i][j], 0, 0, 0);
    __syncthreads();
  }

  float bv[4];
#pragma unroll
  for (int j = 0; j < 4; ++j) bv[j] = bias[n0 + wc * 64 + j * 16 + llo];

#pragma unroll
  for (int i = 0; i < 4; ++i) {
#pragma unroll
    for (int r = 0; r < 4; ++r) {
      const int row = m0 + wr * 64 + i * 16 + lhi * 4 + r;
      if (C_F32 && row >= m_valid) continue;
      const size_t rb = (size_t)row * N + n0 + wc * 64;
#pragma unroll
      for (int j = 0; j < 4; ++j) {
        float v = acc[i][j][r] + bv[j];
        if (C_F32) ((float*)Cout)[rb + j * 16 + llo] = v;
        else       ((ushort*)Cout)[rb + j * 16 + llo] = f2b(v);
      }
    }
  }
}

// ---------------- V transpose pre-pass -------------------------------------
// C1 v-cols [b*Pp+p][h*64+ss]  ->  Vt[(b*Hh+h)*64+ss][p]  (p padded to 640, 0)
__global__ __launch_bounds__(256) void vtrans(const ushort* __restrict__ C1,
                                              ushort* __restrict__ Vt) {
  const int pt = blockIdx.x, h = blockIdx.y, b = blockIdx.z;
  __shared__ ushort Ts[64][72];
  const int t = threadIdx.x;
  const int rl = t >> 2, c16 = (t & 3) * 16;
  const int p = pt * 64 + rl;
  short8 a0 = {0,0,0,0,0,0,0,0}, a1 = {0,0,0,0,0,0,0,0};
  if (p < Pp) {
    const ushort* s = C1 + (size_t)(b * Pp + p) * 2304 + h * 64 + c16;
    a0 = *(const short8*)s;
    a1 = *(const short8*)(s + 8);
  }
  *(short8*)&Ts[rl][c16] = a0;
  *(short8*)&Ts[rl][c16 + 8] = a1;
  __syncthreads();
  const int ss = t >> 2, pc16 = (t & 3) * 16;
  short8 o0, o1;
#pragma unroll
  for (int i = 0; i < 8; ++i) {
    o0[i] = (short)Ts[pc16 + i][ss];
    o1[i] = (short)Ts[pc16 + 8 + i][ss];
  }
  ushort* d = Vt + ((size_t)(b * Hh + h) * 64 + ss) * PKV + pt * 64 + pc16;
  *(short8*)d = o0;
  *(short8*)(d + 8) = o1;
}

// ---------------- flash attention (no-max, deferred-sum) -------------------
// Q,K from C1 (q at +768, k at +1536); V from Vt (transposed, [bh*64+ss][p]).
// O written into C1 v-cols (stride 2304). 64 q-rows/block, 4 waves x 16 rows.
__global__ __launch_bounds__(256) void attn_fwd(
    ushort* C1, const ushort* __restrict__ Vt)
{
  const int qt = blockIdx.x, h = blockIdx.y, b = blockIdx.z;
  const int tid = threadIdx.x;
  const int lane = tid & 63, w = tid >> 6;
  const int llo = lane & 15, lhi = lane >> 4;

  __shared__ ushort Ks[64][72];      // K rows (kv-local x d), padded
  __shared__ ushort Vs[64][72];      // V^T rows (ss x kv-local), padded
  __shared__ ushort Ps[4][16][72];   // per-wave P tile (wave-private)

  const int q0 = qt * 64;
  const int qrow = q0 + w * 16 + llo;   // may exceed 576: finite, never stored
  const size_t qoff = (size_t)(b * Pp + qrow) * 2304 + 768 + h * 64;
  const short8 qf0 = *(const short8*)(C1 + qoff + lhi * 8);
  const short8 qf1 = *(const short8*)(C1 + qoff + 32 + lhi * 8);

  float ls[4] = {0.f, 0.f, 0.f, 0.f};
  floatx4 acc_o[4];
#pragma unroll
  for (int st = 0; st < 4; ++st) acc_o[st] = floatx4{0.f, 0.f, 0.f, 0.f};

  const int srow = tid >> 2;          // 0..63
  const int sc16 = (tid & 3) * 16;
  const ushort* kbase = C1 + (size_t)(b * Pp + srow) * 2304 + 1536 + h * 64 + sc16;
  const ushort* vbase = Vt + ((size_t)(b * Hh + h) * 64 + srow) * PKV + sc16;

  for (int t = 0; t < 10; ++t) {
    const short8 k0 = *(const short8*)(kbase + (size_t)t * 64 * 2304);
    const short8 k1 = *(const short8*)(kbase + (size_t)t * 64 * 2304 + 8);
    const short8 v0 = *(const short8*)(vbase + t * 64);
    const short8 v1 = *(const short8*)(vbase + t * 64 + 8);
    __syncthreads();                  // prev iter QK/PV reads done
    *(short8*)&Ks[srow][sc16] = k0;
    *(short8*)&Ks[srow][sc16 + 8] = k1;
    *(short8*)&Vs[srow][sc16] = v0;
    *(short8*)&Vs[srow][sc16 + 8] = v1;
    __syncthreads();

    // S = Q K^T ; P = exp(S*scale) (no max-sub: |S*scale| <~ 2, fp32-safe)
    float pv[4][4];                   // [ntile][r]
#pragma unroll
    for (int ntl = 0; ntl < 4; ++ntl) {
      floatx4 acc = floatx4{0.f, 0.f, 0.f, 0.f};
      const short8 bf0 = *(const short8*)&Ks[ntl * 16 + llo][lhi * 8];
      const short8 bf1 = *(const short8*)&Ks[ntl * 16 + llo][32 + lhi * 8];
      acc = __builtin_amdgcn_mfma_f32_16x16x32_bf16(qf0, bf0, acc, 0, 0, 0);
      acc = __builtin_amdgcn_mfma_f32_16x16x32_bf16(qf1, bf1, acc, 0, 0, 0);
      const bool valid = (t * 64 + ntl * 16 + llo) < Pp;
#pragma unroll
      for (int r = 0; r < 4; ++r) {
        const float p = valid ? __expf(acc[r] * SCALE) : 0.f;
        pv[ntl][r] = p;
        ls[r] += p;
      }
    }

    // P -> LDS (bf16), wave-private: no barrier needed
#pragma unroll
    for (int r = 0; r < 4; ++r)
#pragma unroll
      for (int ntl = 0; ntl < 4; ++ntl)
        Ps[w][lhi * 4 + r][ntl * 16 + llo] = f2b(pv[ntl][r]);

    // O += P V
    const short8 pa0 = *(const short8*)&Ps[w][llo][lhi * 8];
    const short8 pa1 = *(const short8*)&Ps[w][llo][32 + lhi * 8];
#pragma unroll
    for (int st = 0; st < 4; ++st) {
      const short8 vb0 = *(const short8*)&Vs[st * 16 + llo][lhi * 8];
      const short8 vb1 = *(const short8*)&Vs[st * 16 + llo][32 + lhi * 8];
      acc_o[st] = __builtin_amdgcn_mfma_f32_16x16x32_bf16(pa0, vb0, acc_o[st], 0, 0, 0);
      acc_o[st] = __builtin_amdgcn_mfma_f32_16x16x32_bf16(pa1, vb1, acc_o[st], 0, 0, 0);
    }
  }

  // single deferred sum-reduce across the 16 lanes holding each row
#pragma unroll
  for (int r = 0; r < 4; ++r) {
#pragma unroll
    for (int off = 1; off < 16; off <<= 1) ls[r] += __shfl_xor(ls[r], off, 64);
  }

#pragma unroll
  for (int r = 0; r < 4; ++r) {
    const int p = q0 + w * 16 + lhi * 4 + r;
    if (p < Pp) {
      const float inv = 1.f / ls[r];
      const size_t ob = (size_t)(b * Pp + p) * 2304 + h * 64;  // O into C1 v-cols
#pragma unroll
      for (int st = 0; st < 4; ++st)
        C1[ob + st * 16 + llo] = f2b(acc_o[st][r] * inv);
    }
  }
}

// ---------------- launch ----------------------------------------------------
extern "C" void kernel_launch(void* const* d_in, const int* in_sizes, int n_in,
                              void* d_out, int out_size, void* d_ws, size_t ws_size,
                              hipStream_t stream) {
  const float* x     = (const float*)d_in[0];
  const float* qkv_w = (const float*)d_in[1];
  const float* qkv_b = (const float*)d_in[2];
  const float* out_w = (const float*)d_in[3];
  const float* out_b = (const float*)d_in[4];
  float* out = (float*)d_out;

  char* ws = (char*)d_ws;
  // layout (118.7 MB total, same footprint as the passing round):
  //   C1b  [0, 85.52MB)            qkv output; later O overwrites its v-cols
  //   W3b  [85.52, 86.70)          out_w bf16 (needed until final GEMM)
  //   W1b  [86.70, 90.24)          qkv_w bf16 (dead after QKV GEMM)
  //   Xb   [90.24, 118.75)         x bf16     (dead after QKV GEMM)
  //   Vt   [86.70, 118.16)         overlays W1b+Xb (written after both die)
  ushort* C1b = (ushort*)(ws);
  ushort* W3b = (ushort*)(ws + 85524480);
  ushort* W1b = (ushort*)(ws + 86704128);
  ushort* Xb  = (ushort*)(ws + 90243072);
  ushort* Vtb = (ushort*)(ws + 86704128);

  cvt_pad<<<2048, 256, 0, stream>>>(x, Xb, M_VALID * 768 / 4, M_PAD * 768 / 4);
  cvt_pad<<<1024, 256, 0, stream>>>(qkv_w, W1b, 2304 * 768 / 4, 2304 * 768 / 4);
  cvt_pad<<<512, 256, 0, stream>>>(out_w, W3b, 768 * 768 / 4, 768 * 768 / 4);

  gemm_bt<false><<<dim3(145, 18), 256, 0, stream>>>(Xb, 768, W1b, qkv_b,
                                                    (void*)C1b, 2304, 768, M_PAD);
  vtrans<<<dim3(10, 12, 32), 256, 0, stream>>>(C1b, Vtb);
  attn_fwd<<<dim3(10, 12, 32), 256, 0, stream>>>(C1b, Vtb);
  gemm_bt<true><<<dim3(145, 6), 256, 0, stream>>>(C1b, 2304, W3b, out_b,
                                                  (void*)out, 768, 768, M_VALID);
}

// Round 4
// 350.949 us; speedup vs baseline: 1.2543x; 1.0955x over previous
//
#include <hip/hip_runtime.h>
#include <stdint.h>

typedef __attribute__((ext_vector_type(8))) short short8;
typedef __attribute__((ext_vector_type(4))) float floatx4;

#define DEV static __device__ __forceinline__

constexpr int Bb = 32, Pp = 577, Dd = 768, Hh = 12;
constexpr int M_VALID = Bb * Pp;      // 18464
constexpr int M_PAD   = 18560;        // 145 * 128
constexpr int PKV     = 640;          // padded kv length (10 * 64)
constexpr float SCALE = 0.10206207261596577f;  // 96^-0.5

DEV ushort f2b(float f) {
  union { float f; uint32_t u; } c; c.f = f;
  uint32_t u = c.u + 0x7fffu + ((c.u >> 16) & 1u);
  return (ushort)(u >> 16);
}

// ---------------- fp32 -> bf16 conversion with zero padding ----------------
__global__ void cvt_pad(const float* __restrict__ src, ushort* __restrict__ dst,
                        int n_valid4, int n_total4) {
  const float4* s4 = (const float4*)src;
  for (int i = blockIdx.x * blockDim.x + threadIdx.x; i < n_total4;
       i += gridDim.x * blockDim.x) {
    float4 v = make_float4(0.f, 0.f, 0.f, 0.f);
    if (i < n_valid4) v = s4[i];
    ushort4 o;
    o.x = f2b(v.x); o.y = f2b(v.y); o.z = f2b(v.z); o.w = f2b(v.w);
    ((ushort4*)dst)[i] = o;
  }
}

// ---------------- bf16 GEMM: C[M,N] = A[M,K] * B[N,K]^T + bias -------------
// 128x128 tile, BK=32, 4 waves (2x2), global_load_lds width 16,
// DOUBLE-BUFFERED LDS with counted vmcnt (T3-min) + raw s_barrier,
// 1D grid with bijective chunked XCD swizzle (T1/m204).
#define STAGE(bi, kk)                                                          \
  do {                                                                         \
    __builtin_amdgcn_global_load_lds(                                          \
        (const __attribute__((address_space(1))) void*)(gA0 + (kk)),           \
        (__attribute__((address_space(3))) void*)(As + (bi)*4096 + tid * 8),   \
        16, 0, 0);                                                             \
    __builtin_amdgcn_global_load_lds(                                          \
        (const __attribute__((address_space(1))) void*)(gA1 + (kk)),           \
        (__attribute__((address_space(3))) void*)(As + (bi)*4096 + 2048 + tid * 8), \
        16, 0, 0);                                                             \
    __builtin_amdgcn_global_load_lds(                                          \
        (const __attribute__((address_space(1))) void*)(gB0 + (kk)),           \
        (__attribute__((address_space(3))) void*)(Bs + (bi)*4096 + tid * 8),   \
        16, 0, 0);                                                             \
    __builtin_amdgcn_global_load_lds(                                          \
        (const __attribute__((address_space(1))) void*)(gB1 + (kk)),           \
        (__attribute__((address_space(3))) void*)(Bs + (bi)*4096 + 2048 + tid * 8), \
        16, 0, 0);                                                             \
  } while (0)

template<bool C_F32>
__global__ __launch_bounds__(256) void gemm_bt(
    const ushort* __restrict__ A, int lda,
    const ushort* __restrict__ Bw,
    const float* __restrict__ bias, void* __restrict__ Cout,
    int N, int K, int m_valid, int nt_n)
{
  __shared__ ushort As[2 * 128 * 32];
  __shared__ ushort Bs[2 * 128 * 32];
  const int tid = threadIdx.x;
  const int lane = tid & 63;
  const int w = tid >> 6;
  const int wr = w >> 1, wc = w & 1;
  const int llo = lane & 15, lhi = lane >> 4;

  // bijective chunked XCD swizzle (m204): each XCD gets contiguous wgid run
  {
  }
  const int nwg = gridDim.x;
  const int L = blockIdx.x;
  const int q = nwg >> 3, r = nwg & 7;
  const int xcd = L & 7, pos = L >> 3;
  const int wgid = (xcd < r ? xcd * (q + 1) : r * (q + 1) + (xcd - r) * q) + pos;
  const int m0 = (wgid / nt_n) * 128, n0 = (wgid % nt_n) * 128;

  floatx4 acc[4][4];
#pragma unroll
  for (int i = 0; i < 4; ++i)
#pragma unroll
    for (int j = 0; j < 4; ++j) acc[i][j] = floatx4{0.f, 0.f, 0.f, 0.f};

  const int srow = tid >> 2;          // 0..63
  const int scol = (tid & 3) * 8;     // element offset within 32-wide K slab
  const ushort* gA0 = A  + (size_t)(m0 + srow) * lda + scol;
  const ushort* gA1 = A  + (size_t)(m0 + 64 + srow) * lda + scol;
  const ushort* gB0 = Bw + (size_t)(n0 + srow) * K + scol;
  const ushort* gB1 = Bw + (size_t)(n0 + 64 + srow) * K + scol;

  STAGE(0, 0);
  int cur = 0;
  for (int kk = 0; kk < K; kk += 32) {
    if (kk + 32 < K) {
      STAGE(cur ^ 1, kk + 32);                    // prefetch next tile
      asm volatile("s_waitcnt vmcnt(4)" ::: "memory");  // only current tile's 4
    } else {
      asm volatile("s_waitcnt vmcnt(0)" ::: "memory");
    }
    __builtin_amdgcn_s_barrier();                 // all slices of buf[cur] landed
    __builtin_amdgcn_sched_barrier(0);

    const ushort* Ab = As + cur * 4096;
    const ushort* Bb = Bs + cur * 4096;
    short8 af[4], bfr[4];
#pragma unroll
    for (int i = 0; i < 4; ++i) {
      af[i]  = *(const short8*)(Ab + (wr * 64 + i * 16 + llo) * 32 + lhi * 8);
      bfr[i] = *(const short8*)(Bb + (wc * 64 + i * 16 + llo) * 32 + lhi * 8);
    }
#pragma unroll
    for (int i = 0; i < 4; ++i)
#pragma unroll
      for (int j = 0; j < 4; ++j)
        acc[i][j] = __builtin_amdgcn_mfma_f32_16x16x32_bf16(af[i], bfr[j], acc[i][j], 0, 0, 0);

    __builtin_amdgcn_sched_barrier(0);            // keep ds_reads in this phase
    __builtin_amdgcn_s_barrier();                 // reads done before buf reuse
    cur ^= 1;
  }

  float bv[4];
#pragma unroll
  for (int j = 0; j < 4; ++j) bv[j] = bias[n0 + wc * 64 + j * 16 + llo];

#pragma unroll
  for (int i = 0; i < 4; ++i) {
#pragma unroll
    for (int r2 = 0; r2 < 4; ++r2) {
      const int row = m0 + wr * 64 + i * 16 + lhi * 4 + r2;
      if (C_F32 && row >= m_valid) continue;
      const size_t rb = (size_t)row * N + n0 + wc * 64;
#pragma unroll
      for (int j = 0; j < 4; ++j) {
        float v = acc[i][j][r2] + bv[j];
        if (C_F32) ((float*)Cout)[rb + j * 16 + llo] = v;
        else       ((ushort*)Cout)[rb + j * 16 + llo] = f2b(v);
      }
    }
  }
}

// ---------------- V transpose pre-pass -------------------------------------
// C1 v-cols [b*Pp+p][h*64+ss]  ->  Vt[(b*Hh+h)*64+ss][p]  (p padded to 640, 0)
__global__ __launch_bounds__(256) void vtrans(const ushort* __restrict__ C1,
                                              ushort* __restrict__ Vt) {
  const int pt = blockIdx.x, h = blockIdx.y, b = blockIdx.z;
  __shared__ ushort Ts[64][72];
  const int t = threadIdx.x;
  const int rl = t >> 2, c16 = (t & 3) * 16;
  const int p = pt * 64 + rl;
  short8 a0 = {0,0,0,0,0,0,0,0}, a1 = {0,0,0,0,0,0,0,0};
  if (p < Pp) {
    const ushort* s = C1 + (size_t)(b * Pp + p) * 2304 + h * 64 + c16;
    a0 = *(const short8*)s;
    a1 = *(const short8*)(s + 8);
  }
  *(short8*)&Ts[rl][c16] = a0;
  *(short8*)&Ts[rl][c16 + 8] = a1;
  __syncthreads();
  const int ss = t >> 2, pc16 = (t & 3) * 16;
  short8 o0, o1;
#pragma unroll
  for (int i = 0; i < 8; ++i) {
    o0[i] = (short)Ts[pc16 + i][ss];
    o1[i] = (short)Ts[pc16 + 8 + i][ss];
  }
  ushort* d = Vt + ((size_t)(b * Hh + h) * 64 + ss) * PKV + pt * 64 + pc16;
  *(short8*)d = o0;
  *(short8*)(d + 8) = o1;
}

// ---------------- flash attention (no-max, deferred-sum) -------------------
// Q,K from C1 (q at +768, k at +1536); V from Vt (transposed, [bh*64+ss][p]).
// O written into C1 v-cols (stride 2304). 64 q-rows/block, 4 waves x 16 rows.
__global__ __launch_bounds__(256) void attn_fwd(
    ushort* C1, const ushort* __restrict__ Vt)
{
  const int qt = blockIdx.x, h = blockIdx.y, b = blockIdx.z;
  const int tid = threadIdx.x;
  const int lane = tid & 63, w = tid >> 6;
  const int llo = lane & 15, lhi = lane >> 4;

  __shared__ ushort Ks[64][72];      // K rows (kv-local x d), padded
  __shared__ ushort Vs[64][72];      // V^T rows (ss x kv-local), padded
  __shared__ ushort Ps[4][16][72];   // per-wave P tile (wave-private)

  const int q0 = qt * 64;
  const int qrow = q0 + w * 16 + llo;   // may exceed 576: finite, never stored
  const size_t qoff = (size_t)(b * Pp + qrow) * 2304 + 768 + h * 64;
  const short8 qf0 = *(const short8*)(C1 + qoff + lhi * 8);
  const short8 qf1 = *(const short8*)(C1 + qoff + 32 + lhi * 8);

  float ls[4] = {0.f, 0.f, 0.f, 0.f};
  floatx4 acc_o[4];
#pragma unroll
  for (int st = 0; st < 4; ++st) acc_o[st] = floatx4{0.f, 0.f, 0.f, 0.f};

  const int srow = tid >> 2;          // 0..63
  const int sc16 = (tid & 3) * 16;
  const ushort* kbase = C1 + (size_t)(b * Pp + srow) * 2304 + 1536 + h * 64 + sc16;
  const ushort* vbase = Vt + ((size_t)(b * Hh + h) * 64 + srow) * PKV + sc16;

  for (int t = 0; t < 10; ++t) {
    const short8 k0 = *(const short8*)(kbase + (size_t)t * 64 * 2304);
    const short8 k1 = *(const short8*)(kbase + (size_t)t * 64 * 2304 + 8);
    const short8 v0 = *(const short8*)(vbase + t * 64);
    const short8 v1 = *(const short8*)(vbase + t * 64 + 8);
    __syncthreads();                  // prev iter QK/PV reads done
    *(short8*)&Ks[srow][sc16] = k0;
    *(short8*)&Ks[srow][sc16 + 8] = k1;
    *(short8*)&Vs[srow][sc16] = v0;
    *(short8*)&Vs[srow][sc16 + 8] = v1;
    __syncthreads();

    // S = Q K^T ; P = exp(S*scale) (no max-sub: |S*scale| <~ 2, fp32-safe)
    float pv[4][4];                   // [ntile][r]
#pragma unroll
    for (int ntl = 0; ntl < 4; ++ntl) {
      floatx4 acc = floatx4{0.f, 0.f, 0.f, 0.f};
      const short8 bf0 = *(const short8*)&Ks[ntl * 16 + llo][lhi * 8];
      const short8 bf1 = *(const short8*)&Ks[ntl * 16 + llo][32 + lhi * 8];
      acc = __builtin_amdgcn_mfma_f32_16x16x32_bf16(qf0, bf0, acc, 0, 0, 0);
      acc = __builtin_amdgcn_mfma_f32_16x16x32_bf16(qf1, bf1, acc, 0, 0, 0);
      const bool valid = (t * 64 + ntl * 16 + llo) < Pp;
#pragma unroll
      for (int r = 0; r < 4; ++r) {
        const float p = valid ? __expf(acc[r] * SCALE) : 0.f;
        pv[ntl][r] = p;
        ls[r] += p;
      }
    }

    // P -> LDS (bf16), wave-private: no barrier needed
#pragma unroll
    for (int r = 0; r < 4; ++r)
#pragma unroll
      for (int ntl = 0; ntl < 4; ++ntl)
        Ps[w][lhi * 4 + r][ntl * 16 + llo] = f2b(pv[ntl][r]);

    // O += P V
    const short8 pa0 = *(const short8*)&Ps[w][llo][lhi * 8];
    const short8 pa1 = *(const short8*)&Ps[w][llo][32 + lhi * 8];
#pragma unroll
    for (int st = 0; st < 4; ++st) {
      const short8 vb0 = *(const short8*)&Vs[st * 16 + llo][lhi * 8];
      const short8 vb1 = *(const short8*)&Vs[st * 16 + llo][32 + lhi * 8];
      acc_o[st] = __builtin_amdgcn_mfma_f32_16x16x32_bf16(pa0, vb0, acc_o[st], 0, 0, 0);
      acc_o[st] = __builtin_amdgcn_mfma_f32_16x16x32_bf16(pa1, vb1, acc_o[st], 0, 0, 0);
    }
  }

  // single deferred sum-reduce across the 16 lanes holding each row
#pragma unroll
  for (int r = 0; r < 4; ++r) {
#pragma unroll
    for (int off = 1; off < 16; off <<= 1) ls[r] += __shfl_xor(ls[r], off, 64);
  }

#pragma unroll
  for (int r = 0; r < 4; ++r) {
    const int p = q0 + w * 16 + lhi * 4 + r;
    if (p < Pp) {
      const float inv = 1.f / ls[r];
      const size_t ob = (size_t)(b * Pp + p) * 2304 + h * 64;  // O into C1 v-cols
#pragma unroll
      for (int st = 0; st < 4; ++st)
        C1[ob + st * 16 + llo] = f2b(acc_o[st][r] * inv);
    }
  }
}

// ---------------- launch ----------------------------------------------------
extern "C" void kernel_launch(void* const* d_in, const int* in_sizes, int n_in,
                              void* d_out, int out_size, void* d_ws, size_t ws_size,
                              hipStream_t stream) {
  const float* x     = (const float*)d_in[0];
  const float* qkv_w = (const float*)d_in[1];
  const float* qkv_b = (const float*)d_in[2];
  const float* out_w = (const float*)d_in[3];
  const float* out_b = (const float*)d_in[4];
  float* out = (float*)d_out;

  char* ws = (char*)d_ws;
  // layout (118.7 MB total):
  //   C1b  [0, 85.52MB)            qkv output; later O overwrites its v-cols
  //   W3b  [85.52, 86.70)          out_w bf16 (needed until final GEMM)
  //   W1b  [86.70, 90.24)          qkv_w bf16 (dead after QKV GEMM)
  //   Xb   [90.24, 118.75)         x bf16     (dead after QKV GEMM)
  //   Vt   [86.70, 118.16)         overlays W1b+Xb (written after both die)
  ushort* C1b = (ushort*)(ws);
  ushort* W3b = (ushort*)(ws + 85524480);
  ushort* W1b = (ushort*)(ws + 86704128);
  ushort* Xb  = (ushort*)(ws + 90243072);
  ushort* Vtb = (ushort*)(ws + 86704128);

  cvt_pad<<<2048, 256, 0, stream>>>(x, Xb, M_VALID * 768 / 4, M_PAD * 768 / 4);
  cvt_pad<<<1024, 256, 0, stream>>>(qkv_w, W1b, 2304 * 768 / 4, 2304 * 768 / 4);
  cvt_pad<<<512, 256, 0, stream>>>(out_w, W3b, 768 * 768 / 4, 768 * 768 / 4);

  gemm_bt<false><<<dim3(145 * 18), 256, 0, stream>>>(Xb, 768, W1b, qkv_b,
                                                     (void*)C1b, 2304, 768, M_PAD, 18);
  vtrans<<<dim3(10, 12, 32), 256, 0, stream>>>(C1b, Vtb);
  attn_fwd<<<dim3(10, 12, 32), 256, 0, stream>>>(C1b, Vtb);
  gemm_bt<true><<<dim3(145 * 6), 256, 0, stream>>>(C1b, 2304, W3b, out_b,
                                                   (void*)out, 768, 768, M_VALID, 6);
}